// Round 6
// baseline (325.871 us; speedup 1.0000x reference)
//
#include <hip/hip_runtime.h>
#include <hip/hip_bf16.h>
#include <cmath>

#define LNEPS 1e-5f

typedef __attribute__((ext_vector_type(8))) short short8v;
typedef __attribute__((ext_vector_type(4))) float f32x4;

__device__ __forceinline__ unsigned short f2bf(float f){
  unsigned u = __float_as_uint(f);
  u += 0x7fffu + ((u >> 16) & 1u);
  return (unsigned short)(u >> 16);
}
// tanh-form GELU (max |diff| vs exact erf-GELU ~3e-4 -- invisible in bf16 h).
__device__ __forceinline__ float gelu_f(float x){
  const float y = 0.7978845608028654f * x * (1.f + 0.044715f * x * x);
  const float e = __expf(-2.f * fabsf(y));
  const float t = __builtin_copysignf((1.f - e) / (1.f + e), y);
  return 0.5f * x * (1.f + t);
}

// Device-guarded MFMA wrapper: host pass must never see target builtins.
__device__ __forceinline__ f32x4 mfma32(short8v a, short8v b, f32x4 c){
#ifdef __HIP_DEVICE_COMPILE__
  return __builtin_amdgcn_mfma_f32_16x16x32_bf16(a, b, c, 0, 0, 0);
#else
  return c;
#endif
}

// Stage 128 rows x 128 bf16 from global [r][ldg] into XOR-swizzled LDS (row stride 256B).
__device__ __forceinline__ void stage128(const unsigned short* g, int ldg, short* lds){
  const int t = threadIdx.x;
  #pragma unroll
  for (int it = 0; it < 8; ++it) {
    const int flat = it * 256 + t;
    const int r = flat >> 4, c = flat & 15;
    const uint4 v = *(const uint4*)(g + (size_t)r * ldg + c * 8);
    *(uint4*)((char*)lds + r * 256 + ((c ^ (r & 7)) << 4)) = v;
  }
}
// Swizzled 16B fragment read: row-major [row][128 bf16] (256B rows).
__device__ __forceinline__ short8v frag_ld(const short* lds, int row, int chunk){
  return *(const short8v*)((const char*)lds + row * 256 + ((chunk ^ (row & 7)) << 4));
}
// Swizzled 16B fragment read: row-major [row][64 bf16] (128B rows).
__device__ __forceinline__ short8v frag_ld64(const short* lds, int row, int chunk){
  return *(const short8v*)((const char*)lds + row * 128 + ((chunk ^ (row & 7)) << 4));
}

// ---------------- K0: weights f32 -> bf16 ----------------
__global__ __launch_bounds__(256) void k0_cvt(
    const float* __restrict__ qkvw, const float* __restrict__ pw,
    const float* __restrict__ w1, const float* __restrict__ w2,
    unsigned short* __restrict__ dst)
{
  const int i = (blockIdx.x * 256 + threadIdx.x) * 4;
  const float* src; int off;
  if (i < 49152)       { src = qkvw; off = i; }
  else if (i < 65536)  { src = pw;   off = i - 49152; }
  else if (i < 131072) { src = w1;   off = i - 65536; }
  else                 { src = w2;   off = i - 131072; }
  const float4 v = *(const float4*)(src + off);
  ushort4 o = { f2bf(v.x), f2bf(v.y), f2bf(v.z), f2bf(v.w) };
  *(ushort4*)(dst + i) = o;
}

// ---------------- K1: LN1 + shift + window partition -> win bf16 [131072][128] ----------------
__global__ __launch_bounds__(256) void k1_ln1_window(
    const float* __restrict__ x, const float* __restrict__ gw, const float* __restrict__ gb,
    unsigned short* __restrict__ win)
{
  const int lane = threadIdx.x & 63;
  const int wave = threadIdx.x >> 6;
  const int row  = blockIdx.x * 4 + wave;
  const int wid = row >> 6, n = row & 63;
  const int b = wid >> 10, rem = wid & 1023;
  const int wh = rem >> 5, wwi = rem & 31;
  const int i = n >> 3, j = n & 7;
  const int sh = (wh * 8 + i + 4) & 255;
  const int sw = (wwi * 8 + j + 4) & 255;
  const float2 v = *(const float2*)(x + (((size_t)b << 16) + sh * 256 + sw) * 128 + lane * 2);
  float s = v.x + v.y, ss = v.x * v.x + v.y * v.y;
  #pragma unroll
  for (int o = 1; o < 64; o <<= 1) { s += __shfl_xor(s, o); ss += __shfl_xor(ss, o); }
  const float mean = s * 0.0078125f;
  const float rstd = rsqrtf(ss * 0.0078125f - mean * mean + LNEPS);
  const float2 w2 = *(const float2*)(gw + lane * 2);
  const float2 b2 = *(const float2*)(gb + lane * 2);
  const unsigned lo = f2bf((v.x - mean) * rstd * w2.x + b2.x);
  const unsigned hi = f2bf((v.y - mean) * rstd * w2.y + b2.y);
  *(unsigned*)(win + (size_t)row * 128 + lane * 2) = lo | (hi << 16);
}

// ---------------- K2: qkv MFMA GEMM -> qk bf16 [131072][256] + vt bf16 [16384][16][64] ----------------
__global__ __launch_bounds__(256, 2) void k2_qkv(
    const unsigned short* __restrict__ A,
    const unsigned short* __restrict__ Wb,
    const float* __restrict__ bias,
    unsigned short* __restrict__ qk,
    unsigned short* __restrict__ vt)
{
  __shared__ __align__(16) short At[128 * 128];
  __shared__ __align__(16) short Bt[128 * 128];
  const int t = threadIdx.x;
  const int row0 = blockIdx.x * 128, n0 = blockIdx.y * 128;
  stage128(Wb + (size_t)n0 * 128, 128, At);
  stage128(A + (size_t)row0 * 128, 128, Bt);
  __syncthreads();
  const int l = t & 63, w = t >> 6, w0 = w & 1, w1 = w >> 1;
  const int g = l >> 4, rl = l & 15;
  const f32x4 z = {0.f, 0.f, 0.f, 0.f};
  f32x4 acc[4][4];
  #pragma unroll
  for (int i = 0; i < 4; ++i)
    #pragma unroll
    for (int j = 0; j < 4; ++j) acc[i][j] = z;
  #pragma unroll
  for (int kk = 0; kk < 4; ++kk) {
    short8v a[4], b[4];
    #pragma unroll
    for (int i = 0; i < 4; ++i) a[i] = frag_ld(At, w0 * 64 + i * 16 + rl, kk * 4 + g);
    #pragma unroll
    for (int j = 0; j < 4; ++j) b[j] = frag_ld(Bt, w1 * 64 + j * 16 + rl, kk * 4 + g);
    #pragma unroll
    for (int i = 0; i < 4; ++i)
      #pragma unroll
      for (int j = 0; j < 4; ++j)
        acc[i][j] = mfma32(a[i], b[j], acc[i][j]);
  }
  if (blockIdx.y < 2) {
    #pragma unroll
    for (int i = 0; i < 4; ++i) {
      const int np = w0 * 64 + i * 16 + 4 * g;
      const float4 bv = *(const float4*)(bias + n0 + np);
      #pragma unroll
      for (int j = 0; j < 4; ++j) {
        const int r = row0 + w1 * 64 + j * 16 + rl;
        ushort4 o = { f2bf(acc[i][j][0] + bv.x), f2bf(acc[i][j][1] + bv.y),
                      f2bf(acc[i][j][2] + bv.z), f2bf(acc[i][j][3] + bv.w) };
        *(ushort4*)(qk + (size_t)r * 256 + n0 + np) = o;
      }
    }
  } else {
    #pragma unroll
    for (int i = 0; i < 4; ++i) {
      const int np = w0 * 64 + i * 16 + 4 * g;
      const int h = np >> 4, db = np & 15;
      const float4 bv = *(const float4*)(bias + 256 + np);
      const float ba[4] = {bv.x, bv.y, bv.z, bv.w};
      #pragma unroll
      for (int j = 0; j < 4; ++j) {
        const int r = row0 + w1 * 64 + j * 16 + rl;
        const int wn = r >> 6, m = r & 63;
        unsigned short* dst = vt + (((size_t)wn * 8 + h) << 10) + m;
        #pragma unroll
        for (int e = 0; e < 4; ++e)
          dst[(db + e) * 64] = f2bf(acc[i][j][e] + ba[e]);
      }
    }
  }
}

// ---------------- K3: MFMA window attention (16x16x32 only), one wave per (window, head) ----------------
__global__ __launch_bounds__(256, 2) void k3_attn(
    const unsigned short* __restrict__ qk,
    const unsigned short* __restrict__ vt,
    const float* __restrict__ table,
    unsigned short* __restrict__ attn)
{
  __shared__ float Tb[1800];
  __shared__ __align__(16) unsigned short Pl[4][4096];   // per-wave P [r][m] bf16, XOR-swizzled
  const int t = threadIdx.x;
  for (int i = t; i < 1800; i += 256) Tb[i] = table[i];
  __syncthreads();
  const int l = t & 63, w = t >> 6;
  const int id = blockIdx.x * 4 + w;
  const int win = id >> 3, h = id & 7;
  const int g = l >> 4, rl = l & 15;
  // ---- QK^T via 16x16x32, K zero-padded (head_dim = 16 -> lanes g>=2 hold zeros) ----
  const unsigned short* qbase = qk + (size_t)win * 64 * 256 + h * 16;
  const short8v zz = {0,0,0,0,0,0,0,0};
  short8v qf[4], kf[4];
  if (g < 2) {
    #pragma unroll
    for (int rf = 0; rf < 4; ++rf)
      qf[rf] = *(const short8v*)(qbase + (size_t)(rf * 16 + rl) * 256 + g * 8);
    #pragma unroll
    for (int mf = 0; mf < 4; ++mf)
      kf[mf] = *(const short8v*)(qbase + 128 + (size_t)(mf * 16 + rl) * 256 + g * 8);
  } else {
    #pragma unroll
    for (int i = 0; i < 4; ++i) { qf[i] = zz; kf[i] = zz; }
  }
  const f32x4 z = {0.f, 0.f, 0.f, 0.f};
  f32x4 s[4][4];
  #pragma unroll
  for (int mf = 0; mf < 4; ++mf)
    #pragma unroll
    for (int rf = 0; rf < 4; ++rf)
      s[mf][rf] = mfma32(kf[mf], qf[rf], z);   // S^T: m = mf*16+4g+e, r = rf*16+rl
  // ---- bias + softmax (m runs over lanes sharing rl: xor 16/32) ----
  float sum[4];
  #pragma unroll
  for (int rf = 0; rf < 4; ++rf) {
    const int r = rf * 16 + rl, i1 = r >> 3, j1 = r & 7;
    float mx = -1e30f;
    #pragma unroll
    for (int mf = 0; mf < 4; ++mf)
      #pragma unroll
      for (int e = 0; e < 4; ++e) {
        const int m = mf * 16 + g * 4 + e;
        const int i2 = m >> 3, j2 = m & 7;
        const float v = s[mf][rf][e] * 0.25f + Tb[((i1 - i2 + 7) * 15 + (j1 - j2 + 7)) * 8 + h];
        s[mf][rf][e] = v;
        mx = fmaxf(mx, v);
      }
    mx = fmaxf(mx, __shfl_xor(mx, 16));
    mx = fmaxf(mx, __shfl_xor(mx, 32));
    float sm = 0.f;
    #pragma unroll
    for (int mf = 0; mf < 4; ++mf)
      #pragma unroll
      for (int e = 0; e < 4; ++e) {
        const float ev = __expf(s[mf][rf][e] - mx);
        s[mf][rf][e] = ev;
        sm += ev;
      }
    sm += __shfl_xor(sm, 16);
    sm += __shfl_xor(sm, 32);
    sum[rf] = sm;
  }
  // ---- pack P to bf16 and round-trip through per-wave LDS (intra-wave, no barrier) ----
  char* Pw = (char*)&Pl[w][0];
  #pragma unroll
  for (int rf = 0; rf < 4; ++rf) {
    const int r = rf * 16 + rl;
    const int swz = (r & 7) << 4;
    #pragma unroll
    for (int mf = 0; mf < 4; ++mf) {
      uint2 u;
      u.x = (unsigned)f2bf(s[mf][rf][0]) | ((unsigned)f2bf(s[mf][rf][1]) << 16);
      u.y = (unsigned)f2bf(s[mf][rf][2]) | ((unsigned)f2bf(s[mf][rf][3]) << 16);
      *(uint2*)(Pw + ((r * 128 + mf * 32 + g * 8) ^ swz)) = u;
    }
  }
  // ---- PV: O^T = V^T (A) x P^T (B), K = 32, 2 K-blocks ----
  const unsigned short* vb = vt + (((size_t)win * 8 + h) << 10) + rl * 64 + g * 8;
  f32x4 o[4];
  #pragma unroll
  for (int rf = 0; rf < 4; ++rf) o[rf] = z;
  #pragma unroll
  for (int c = 0; c < 2; ++c) {
    const short8v va = *(const short8v*)(vb + c * 32);
    #pragma unroll
    for (int rf = 0; rf < 4; ++rf) {
      const int r = rf * 16 + rl;
      const short8v pb = *(const short8v*)(Pw + ((r * 128 + c * 64 + g * 16) ^ ((r & 7) << 4)));
      o[rf] = mfma32(va, pb, o[rf]);
    }
  }
  #pragma unroll
  for (int rf = 0; rf < 4; ++rf) {
    const float inv = 1.f / sum[rf];
    const int r = rf * 16 + rl;
    ushort4 ov = { f2bf(o[rf][0] * inv), f2bf(o[rf][1] * inv),
                   f2bf(o[rf][2] * inv), f2bf(o[rf][3] * inv) };
    *(ushort4*)(attn + ((size_t)win * 64 + r) * 128 + h * 16 + g * 4) = ov;
  }
}

// ---------------- K4: proj MFMA + window reverse + unshift + residual -> d_out (f32) ----------------
__global__ __launch_bounds__(256, 2) void k4_proj(
    const unsigned short* __restrict__ A,
    const unsigned short* __restrict__ Wb,
    const float* __restrict__ bias,
    const float* __restrict__ xin,
    float* __restrict__ out)
{
  __shared__ __align__(16) short At[128 * 128];
  __shared__ __align__(16) short Bt[128 * 128];
  const int t = threadIdx.x;
  const int row0 = blockIdx.x * 128;
  stage128(Wb, 128, At);
  stage128(A + (size_t)row0 * 128, 128, Bt);
  __syncthreads();
  const int l = t & 63, w = t >> 6, w0 = w & 1, w1 = w >> 1;
  const int g = l >> 4, rl = l & 15;
  const f32x4 z = {0.f, 0.f, 0.f, 0.f};
  f32x4 acc[4][4];
  #pragma unroll
  for (int i = 0; i < 4; ++i)
    #pragma unroll
    for (int j = 0; j < 4; ++j) acc[i][j] = z;
  #pragma unroll
  for (int kk = 0; kk < 4; ++kk) {
    short8v a[4], b[4];
    #pragma unroll
    for (int i = 0; i < 4; ++i) a[i] = frag_ld(At, w0 * 64 + i * 16 + rl, kk * 4 + g);
    #pragma unroll
    for (int j = 0; j < 4; ++j) b[j] = frag_ld(Bt, w1 * 64 + j * 16 + rl, kk * 4 + g);
    #pragma unroll
    for (int i = 0; i < 4; ++i)
      #pragma unroll
      for (int j = 0; j < 4; ++j)
        acc[i][j] = mfma32(a[i], b[j], acc[i][j]);
  }
  #pragma unroll
  for (int i = 0; i < 4; ++i) {
    const int c = w0 * 64 + i * 16 + 4 * g;
    const float4 bv = *(const float4*)(bias + c);
    #pragma unroll
    for (int j = 0; j < 4; ++j) {
      const int r = row0 + w1 * 64 + j * 16 + rl;
      const int wn = r >> 6, n = r & 63;
      const int b_ = wn >> 10, rem = wn & 1023;
      const int wh = rem >> 5, ww = rem & 31;
      const int si = n >> 3, sj = n & 7;
      const int hd = (wh * 8 + si + 4) & 255;
      const int wd = (ww * 8 + sj + 4) & 255;
      const size_t off = (((size_t)b_ << 16) + hd * 256 + wd) * 128 + c;
      const float4 xv = *(const float4*)(xin + off);
      float4 o = { xv.x + acc[i][j][0] + bv.x, xv.y + acc[i][j][1] + bv.y,
                   xv.z + acc[i][j][2] + bv.z, xv.w + acc[i][j][3] + bv.w };
      *(float4*)(out + off) = o;
    }
  }
}

// ---------------- K5: fused LN2 + fc1 + GELU + fc2 + residual (MFMA, 8-phase, 4 blocks/CU) ----------------
// Per phase s (64 fc1-cols == 64 fc2-k): T14 reg-staged weight tiles, wave-local h.
__global__ __launch_bounds__(256, 4) void k5_mlp(
    const float* x2,
    const float* __restrict__ gw, const float* __restrict__ gb,
    const unsigned short* __restrict__ w1b, const float* __restrict__ b1,
    const unsigned short* __restrict__ w2b, const float* __restrict__ b2,
    float* out)
{
  __shared__ __align__(16) short Xt[64 * 128];   // 16 KB ln2(x2), swizzled 256B rows
  __shared__ __align__(16) short Ht[64 * 64];    // 8 KB h-slice, swizzled 128B rows
  __shared__ __align__(16) short Wt[8192];       // 16 KB W1-slice(64x128) / W2-slice(128x64)
  const int t = threadIdx.x;
  const size_t row0 = (size_t)blockIdx.x * 64;

  // T14: issue W1[0] loads first so they fly under the LN stage.
  uint4 wr[4];
  {
    const int r = t >> 2, c4 = (t & 3) * 4;           // W1 tile: 64 rows x 16 chunks
    #pragma unroll
    for (int q = 0; q < 4; ++q)
      wr[q] = *(const uint4*)(w1b + (size_t)r * 128 + (c4 + q) * 8);
  }

  {
    // LN2: 4 threads per row over 64 rows.
    const int rr = t >> 2, qq = t & 3;
    const float* src = x2 + (row0 + rr) * 128 + qq * 32;
    float v[32]; float s = 0.f, ss = 0.f;
    #pragma unroll
    for (int q = 0; q < 8; ++q) {
      const float4 a4 = *(const float4*)(src + q * 4);
      v[q*4+0] = a4.x; v[q*4+1] = a4.y; v[q*4+2] = a4.z; v[q*4+3] = a4.w;
      s  += a4.x + a4.y + a4.z + a4.w;
      ss += a4.x*a4.x + a4.y*a4.y + a4.z*a4.z + a4.w*a4.w;
    }
    s += __shfl_xor(s, 1); ss += __shfl_xor(ss, 1);
    s += __shfl_xor(s, 2); ss += __shfl_xor(ss, 2);
    const float mean = s * 0.0078125f;
    const float rstd = rsqrtf(ss * 0.0078125f - mean * mean + LNEPS);
    #pragma unroll
    for (int cc = 0; cc < 4; ++cc) {
      const int col = qq * 32 + cc * 8;
      const float4 g0 = *(const float4*)(gw + col), g1 = *(const float4*)(gw + col + 4);
      const float4 c0 = *(const float4*)(gb + col), c1 = *(const float4*)(gb + col + 4);
      uint4 pk;
      pk.x = (unsigned)f2bf((v[cc*8+0]-mean)*rstd*g0.x + c0.x)
           | ((unsigned)f2bf((v[cc*8+1]-mean)*rstd*g0.y + c0.y) << 16);
      pk.y = (unsigned)f2bf((v[cc*8+2]-mean)*rstd*g0.z + c0.z)
           | ((unsigned)f2bf((v[cc*8+3]-mean)*rstd*g0.w + c0.w) << 16);
      pk.z = (unsigned)f2bf((v[cc*8+4]-mean)*rstd*g1.x + c1.x)
           | ((unsigned)f2bf((v[cc*8+5]-mean)*rstd*g1.y + c1.y) << 16);
      pk.w = (unsigned)f2bf((v[cc*8+6]-mean)*rstd*g1.z + c1.z)
           | ((unsigned)f2bf((v[cc*8+7]-mean)*rstd*g1.w + c1.w) << 16);
      const int chunk = qq * 4 + cc;
      *(uint4*)((char*)Xt + rr * 256 + ((chunk ^ (rr & 7)) << 4)) = pk;
    }
  }

  const int wv = t >> 6, l = t & 63;
  const int g = l >> 4, rl = l & 15;
  const int wrow = wv * 16 + rl;                       // this lane's row for B-frags / output
  // Stage-write/load address precompute
  const int w1r = t >> 2, w1c = (t & 3) * 4;           // W1: r in 0..63, chunks w1c..w1c+3
  const int w2r = t >> 1, w2c = (t & 1) * 4;           // W2: r in 0..127, chunks w2c..w2c+3

  // W1[0] was loaded above; Wt is virgin -> write without a barrier.
  #pragma unroll
  for (int q = 0; q < 4; ++q)
    *(uint4*)((char*)Wt + w1r * 256 + (((w1c + q) ^ (w1r & 7)) << 4)) = wr[q];
  // Issue W2[0] loads (consumed after fc1 phase 0).
  #pragma unroll
  for (int q = 0; q < 4; ++q)
    wr[q] = *(const uint4*)(w2b + (size_t)w2r * 512 + (w2c + q) * 8);
  __syncthreads();    // Xt + W1[0] ready

  const f32x4 z = {0.f, 0.f, 0.f, 0.f};
  f32x4 oacc[8];
  #pragma unroll
  for (int i = 0; i < 8; ++i) oacc[i] = z;

  for (int s = 0; s < 8; ++s) {
    // ---- fc1: h-slice = ln2(x) @ W1[s*64..]^T, out 64 rows x 64 cols ----
    f32x4 hacc[4];
    #pragma unroll
    for (int i = 0; i < 4; ++i) hacc[i] = z;
    #pragma unroll
    for (int kk = 0; kk < 4; ++kk) {
      const short8v b = frag_ld(Xt, wrow, kk * 4 + g);
      #pragma unroll
      for (int i = 0; i < 4; ++i) {
        const short8v a = frag_ld(Wt, i * 16 + rl, kk * 4 + g);
        hacc[i] = mfma32(a, b, hacc[i]);
      }
    }
    // GELU -> Ht (wave-local rows; intra-wave, no barrier needed before fc2)
    #pragma unroll
    for (int i = 0; i < 4; ++i) {
      const float4 b1v = *(const float4*)(b1 + s * 64 + i * 16 + 4 * g);
      uint2 u;
      u.x = (unsigned)f2bf(gelu_f(hacc[i][0] + b1v.x))
          | ((unsigned)f2bf(gelu_f(hacc[i][1] + b1v.y)) << 16);
      u.y = (unsigned)f2bf(gelu_f(hacc[i][2] + b1v.z))
          | ((unsigned)f2bf(gelu_f(hacc[i][3] + b1v.w)) << 16);
      *(uint2*)((char*)Ht + wrow * 128 + ((i * 32 + g * 8) ^ ((wrow & 7) << 4))) = u;
    }
    __syncthreads();   // all waves done reading W1[s] -> Wt free
    // Write W2[s] from regs; issue W1[s+1] loads (hidden under fc2 MFMA).
    #pragma unroll
    for (int q = 0; q < 4; ++q)
      *(uint4*)((char*)Wt + w2r * 128 + (((w2c + q) ^ (w2r & 7)) << 4)) = wr[q];
    if (s < 7) {
      #pragma unroll
      for (int q = 0; q < 4; ++q)
        wr[q] = *(const uint4*)(w1b + (size_t)(s + 1) * 8192 + (size_t)w1r * 128 + (w1c + q) * 8);
    }
    __syncthreads();   // W2[s] ready
    // ---- fc2 partial: oacc += h_slice @ W2[:, s*64..]^T (K = 64) ----
    #pragma unroll
    for (int kk = 0; kk < 2; ++kk) {
      const short8v b = frag_ld64(Ht, wrow, kk * 4 + g);
      #pragma unroll
      for (int i = 0; i < 8; ++i) {
        const short8v a = frag_ld64(Wt, i * 16 + rl, kk * 4 + g);
        oacc[i] = mfma32(a, b, oacc[i]);
      }
    }
    if (s < 7) {
      __syncthreads(); // all waves done reading W2[s]
      #pragma unroll
      for (int q = 0; q < 4; ++q)
        *(uint4*)((char*)Wt + w1r * 256 + (((w1c + q) ^ (w1r & 7)) << 4)) = wr[q];
      #pragma unroll
      for (int q = 0; q < 4; ++q)
        wr[q] = *(const uint4*)(w2b + (size_t)w2r * 512 + (s + 1) * 64 + (w2c + q) * 8);
      __syncthreads(); // W1[s+1] ready
    }
  }

  // ---- epilogue: out = x2 + oacc + b2 ----
  const size_t orow = row0 + wrow;
  #pragma unroll
  for (int i = 0; i < 8; ++i) {
    const int c = i * 16 + 4 * g;
    const float4 bv = *(const float4*)(b2 + c);
    const float4 xv = *(const float4*)(x2 + orow * 128 + c);
    float4 o = { xv.x + oacc[i][0] + bv.x, xv.y + oacc[i][1] + bv.y,
                 xv.z + oacc[i][2] + bv.z, xv.w + oacc[i][3] + bv.w };
    *(float4*)(out + orow * 128 + c) = o;
  }
}

extern "C" void kernel_launch(void* const* d_in, const int* in_sizes, int n_in,
                              void* d_out, int out_size, void* d_ws, size_t ws_size,
                              hipStream_t stream)
{
  const float* x    = (const float*)d_in[0];
  const float* n1w  = (const float*)d_in[1];
  const float* n1b  = (const float*)d_in[2];
  const float* qkvw = (const float*)d_in[3];
  const float* qkvB = (const float*)d_in[4];
  const float* relb = (const float*)d_in[5];
  const float* pw   = (const float*)d_in[6];
  const float* pb   = (const float*)d_in[7];
  const float* n2w  = (const float*)d_in[8];
  const float* n2b  = (const float*)d_in[9];
  const float* w1   = (const float*)d_in[10];
  const float* b1   = (const float*)d_in[11];
  const float* w2   = (const float*)d_in[12];
  const float* b2   = (const float*)d_in[13];
  float* out = (float*)d_out;

  unsigned short* winb = (unsigned short*)d_ws;        // 16,777,216 el (LN1 out; reused as attn out)
  unsigned short* qkb  = winb + 16777216;              // 33,554,432 el  Q|K interleaved [row][256]
  unsigned short* vtb  = qkb + 33554432;               // 16,777,216 el  V^T per (win,head): [16][64]
  unsigned short* wb   = vtb + 16777216;               // 196,608 el  bf16 weights
  unsigned short* qkvw_b = wb;
  unsigned short* pw_b   = wb + 49152;
  unsigned short* w1_b   = wb + 65536;
  unsigned short* w2_b   = wb + 131072;

  k0_cvt<<<192, 256, 0, stream>>>(qkvw, pw, w1, w2, wb);
  k1_ln1_window<<<32768, 256, 0, stream>>>(x, n1w, n1b, winb);
  k2_qkv<<<dim3(1024, 3), 256, 0, stream>>>(winb, qkvw_b, qkvB, qkb, vtb);
  k3_attn<<<4096, 256, 0, stream>>>(qkb, vtb, relb, winb);
  k4_proj<<<1024, 256, 0, stream>>>(winb, pw_b, pb, x, out);
  k5_mlp<<<2048, 256, 0, stream>>>(out, n2w, n2b, w1_b, b1, w2_b, b2, out);
}